// Round 1
// baseline (28.812 us; speedup 1.0000x reference)
//
#include <hip/hip_runtime.h>

// CyclicShiftConv collapse:
//   Each rot_idx row is a permutation of [0,L) => s[b,c,r] is r-independent
//   => scores constant over r => softmax over R=4 equals exactly 0.25.
//   out[b,c,l] = 0.25 * sum_r x[b,c, rot_idx[r,l]].
// Pure memory-bound gather-average. w1/b1/w2/b2 are mathematically dead
// (softmax of identical logits is 1/R regardless of the MLP).

constexpr int Lconst = 4096;   // N*N
constexpr int BC     = 16 * 256;  // B*C rows

__global__ __launch_bounds__(256) void rotavg_kernel(
    const float* __restrict__ x,
    const int*   __restrict__ rot_idx,
    float*       __restrict__ out) {
  __shared__ float row[Lconst];

  const int bc = blockIdx.x;            // (b,c) row id
  const float* xr = x + (size_t)bc * Lconst;
  float*       o  = out + (size_t)bc * Lconst;
  const int t = threadIdx.x;

  // Stage this row into LDS: 4096 floats = 256 thr * 4 iters * float4.
  const float4* xr4  = reinterpret_cast<const float4*>(xr);
  float4*       row4 = reinterpret_cast<float4*>(row);
#pragma unroll
  for (int i = 0; i < 4; ++i) {
    row4[t + i * 256] = xr4[t + i * 256];
  }
  __syncthreads();

  const int4* idx0 = reinterpret_cast<const int4*>(rot_idx);
  const int4* idx1 = reinterpret_cast<const int4*>(rot_idx + Lconst);
  const int4* idx2 = reinterpret_cast<const int4*>(rot_idx + 2 * Lconst);
  const int4* idx3 = reinterpret_cast<const int4*>(rot_idx + 3 * Lconst);
  float4* o4 = reinterpret_cast<float4*>(o);

#pragma unroll
  for (int i = 0; i < 4; ++i) {
    const int e = t + i * 256;          // float4 slot within the row
    const int4 a = idx0[e];
    const int4 b = idx1[e];
    const int4 c = idx2[e];
    const int4 d = idx3[e];
    float4 v;
    v.x = 0.25f * (row[a.x] + row[b.x] + row[c.x] + row[d.x]);
    v.y = 0.25f * (row[a.y] + row[b.y] + row[c.y] + row[d.y]);
    v.z = 0.25f * (row[a.z] + row[b.z] + row[c.z] + row[d.z]);
    v.w = 0.25f * (row[a.w] + row[b.w] + row[c.w] + row[d.w]);
    o4[e] = v;
  }
}

extern "C" void kernel_launch(void* const* d_in, const int* in_sizes, int n_in,
                              void* d_out, int out_size, void* d_ws, size_t ws_size,
                              hipStream_t stream) {
  const float* x       = (const float*)d_in[0];
  const int*   rot_idx = (const int*)d_in[1];
  // d_in[2..5] = w1, b1, w2, b2 — unused (see collapse proof above).
  float* out = (float*)d_out;

  rotavg_kernel<<<BC, 256, 0, stream>>>(x, rot_idx, out);
}